// Round 1
// baseline (106.772 us; speedup 1.0000x reference)
//
#include <hip/hip_runtime.h>

// GARCH(1,1) path generation, 3 independent series, N = 24*131072 steps each.
//   v_t = omega + alpha*p_{t-1}^2 + beta*v_{t-1};  p_t = mu + z_t*sqrt(v_t); p_0 = 0.
// Output layout: out[s*N + t] = p_t of series s (flat reinterpret as (B,24,3)).
//
// Parallelization: contraction/burn-in. Each thread owns K_OUT consecutive
// outputs of one series, started WARM steps early from a steady-state guess.
// State error decays by ~(alpha*z^2+beta) per step; over 768 steps residual
// error < 1e-9 even at worst-case params (alpha+beta<=0.96) at +4.5 sigma.
// Chunks whose warmup would cross t=0 replay exactly from the true (0,0) state.

#define K_OUT 256
#define WARM  768

__global__ __launch_bounds__(64, 1) void garch_scan_kernel(
    const float* __restrict__ params,   // (3,4): [mu, omega, alpha, beta] per series
    const float* __restrict__ noise,    // (3,N) flat
    float* __restrict__ out,            // (3,N) flat
    int N)
{
    const int cps = N / K_OUT;                    // chunks per series
    const int gid = blockIdx.x * 64 + threadIdx.x;
    if (gid >= 3 * cps) return;
    const int s = gid / cps;
    const int c = gid - s * cps;

    const float mu    = params[s * 4 + 0];
    const float omega = params[s * 4 + 1];
    const float alpha = params[s * 4 + 2];
    const float beta  = params[s * 4 + 3];

    const float*  z  = noise + (size_t)s * N;
    const float4* z4 = (const float4*)z;
    float*        o  = out + (size_t)s * N;
    float4*       o4 = (float4*)o;

    const int ostart = c * K_OUT;

    float p, v;
    int t;

    if (c == 0) {
        // exact from t=0; p_0 = 0 is written directly
        p = 0.0f; v = 0.0f;
        o[0] = 0.0f;
        #pragma unroll
        for (int j = 1; j <= 3; ++j) {
            v = fmaf(alpha, p * p, fmaf(beta, v, omega));
            p = fmaf(z[j], sqrtf(v), mu);
            o[j] = p;
        }
        for (t = 4; t < K_OUT; t += 4) {
            float4 zq = z4[t >> 2];
            float4 pq;
            v = fmaf(alpha, p*p, fmaf(beta, v, omega)); p = fmaf(zq.x, sqrtf(v), mu); pq.x = p;
            v = fmaf(alpha, p*p, fmaf(beta, v, omega)); p = fmaf(zq.y, sqrtf(v), mu); pq.y = p;
            v = fmaf(alpha, p*p, fmaf(beta, v, omega)); p = fmaf(zq.z, sqrtf(v), mu); pq.z = p;
            v = fmaf(alpha, p*p, fmaf(beta, v, omega)); p = fmaf(zq.w, sqrtf(v), mu); pq.w = p;
            o4[t >> 2] = pq;
        }
        return;
    }

    if (ostart <= WARM) {
        // warmup window would cross t=0: replay exactly from the true init
        p = 0.0f; v = 0.0f;
        t = 1;
    } else {
        // steady-state guess; contraction washes out the error over WARM steps
        p = 0.0f;
        v = omega / fmaxf(1.0f - alpha - beta, 0.02f);
        t = ostart - WARM + 1;                    // tinit % 4 == 0, so t % 4 == 1
    }

    // --- warmup: advance state to t = ostart-1 (no stores) ---
    for (; t < ostart && (t & 3); ++t) {          // peel to float4 alignment
        v = fmaf(alpha, p * p, fmaf(beta, v, omega));
        p = fmaf(z[t], sqrtf(v), mu);
    }
    for (; t < ostart; t += 4) {
        float4 zq = z4[t >> 2];
        v = fmaf(alpha, p*p, fmaf(beta, v, omega)); p = fmaf(zq.x, sqrtf(v), mu);
        v = fmaf(alpha, p*p, fmaf(beta, v, omega)); p = fmaf(zq.y, sqrtf(v), mu);
        v = fmaf(alpha, p*p, fmaf(beta, v, omega)); p = fmaf(zq.z, sqrtf(v), mu);
        v = fmaf(alpha, p*p, fmaf(beta, v, omega)); p = fmaf(zq.w, sqrtf(v), mu);
    }

    // --- output phase: t == ostart (4-aligned), K_OUT steps with stores ---
    const int tend = ostart + K_OUT;
    for (; t < tend; t += 4) {
        float4 zq = z4[t >> 2];
        float4 pq;
        v = fmaf(alpha, p*p, fmaf(beta, v, omega)); p = fmaf(zq.x, sqrtf(v), mu); pq.x = p;
        v = fmaf(alpha, p*p, fmaf(beta, v, omega)); p = fmaf(zq.y, sqrtf(v), mu); pq.y = p;
        v = fmaf(alpha, p*p, fmaf(beta, v, omega)); p = fmaf(zq.z, sqrtf(v), mu); pq.z = p;
        v = fmaf(alpha, p*p, fmaf(beta, v, omega)); p = fmaf(zq.w, sqrtf(v), mu); pq.w = p;
        o4[t >> 2] = pq;
    }
}

extern "C" void kernel_launch(void* const* d_in, const int* in_sizes, int n_in,
                              void* d_out, int out_size, void* d_ws, size_t ws_size,
                              hipStream_t stream) {
    const float* params = (const float*)d_in[0];
    const float* noise  = (const float*)d_in[1];
    float* out = (float*)d_out;

    const int N = in_sizes[1] / 3;          // 3,145,728
    const int cps = N / K_OUT;              // 12,288
    const int total = 3 * cps;              // 36,864 threads
    const int block = 64;
    const int grid = (total + block - 1) / block;

    garch_scan_kernel<<<grid, block, 0, stream>>>(params, noise, out, N);
}